// Round 1
// baseline (1030.596 us; speedup 1.0000x reference)
//
#include <hip/hip_runtime.h>
#include <math.h>

#define NNODES 50000
#define IND    128
#define NH     8
#define OD     16
#define HD     128          // NH*OD
#define NEDGE  1600000
#define ETOT   (NEDGE + NNODES)

// ---------------- Kernel 0: reduce Qw over heads -> Wsum[16][128], Bsum[16] ----
__global__ __launch_bounds__(256) void prep_kernel(
    const float* __restrict__ Qw, const float* __restrict__ Qb,
    float* __restrict__ Wsum, float* __restrict__ Bsum)
{
    for (int idx = threadIdx.x; idx < OD * IND; idx += 256) {
        int dd = idx >> 7;          // /128
        int k  = idx & 127;
        float s = 0.f;
#pragma unroll
        for (int hh = 0; hh < NH; hh++) s += Qw[(hh * OD + dd) * IND + k];
        Wsum[idx] = s;
    }
    if (threadIdx.x < OD) {
        float s = 0.f;
#pragma unroll
        for (int hh = 0; hh < NH; hh++) s += Qb[hh * OD + threadIdx.x];
        Bsum[threadIdx.x] = s;
    }
}

// ---------------- Kernel A: K/V/Qsum projections ------------------------------
// 32-node tile per block; h staged in LDS (broadcast reads);
// thread t: col i = t&127, node-group rg = t>>7 (16 nodes each).
__global__ __launch_bounds__(256) void proj_kernel(
    const float* __restrict__ hmat,
    const float* __restrict__ Kw, const float* __restrict__ Kb,
    const float* __restrict__ Vw, const float* __restrict__ Vb,
    const float* __restrict__ Wsum, const float* __restrict__ Bsum,
    float* __restrict__ Kbuf, float* __restrict__ Vbuf, float* __restrict__ Qs)
{
    __shared__ float hs[32 * IND];
    const int n0 = blockIdx.x * 32;

    for (int idx = threadIdx.x; idx < 32 * IND / 4; idx += 256) {
        int nn = n0 + (idx >> 5);                  // idx*4/128
        float4 v = make_float4(0.f, 0.f, 0.f, 0.f);
        if (nn < NNODES) v = ((const float4*)hmat)[(size_t)n0 * 32 + idx];
        ((float4*)hs)[idx] = v;
    }
    __syncthreads();

    const int i  = threadIdx.x & 127;
    const int rg = threadIdx.x >> 7;               // 0 or 1

    float accK[16], accV[16], accQ[16];
#pragma unroll
    for (int j = 0; j < 16; j++) { accK[j] = 0.f; accV[j] = 0.f; accQ[j] = 0.f; }

    const float4* wkp = (const float4*)(Kw + (size_t)i * IND);
    const float4* wvp = (const float4*)(Vw + (size_t)i * IND);
    const float4* wqp = (const float4*)(Wsum + (size_t)(i & 15) * IND); // valid for all lanes

    for (int kq = 0; kq < IND / 4; kq++) {
        float4 wk = wkp[kq];
        float4 wv = wvp[kq];
        float4 wq = wqp[kq];
        const float* hb = hs + rg * 16 * IND + kq * 4;
#pragma unroll
        for (int j = 0; j < 16; j++) {
            float4 hh = *(const float4*)(hb + j * IND);
            accK[j] = fmaf(hh.w, wk.w, fmaf(hh.z, wk.z, fmaf(hh.y, wk.y, fmaf(hh.x, wk.x, accK[j]))));
            accV[j] = fmaf(hh.w, wv.w, fmaf(hh.z, wv.z, fmaf(hh.y, wv.y, fmaf(hh.x, wv.x, accV[j]))));
            accQ[j] = fmaf(hh.w, wq.w, fmaf(hh.z, wq.z, fmaf(hh.y, wq.y, fmaf(hh.x, wq.x, accQ[j]))));
        }
    }

    const float kb = Kb[i];
    const float vb = Vb[i];
    const float qb = Bsum[i & 15];
#pragma unroll
    for (int j = 0; j < 16; j++) {
        int nn = n0 + rg * 16 + j;
        if (nn < NNODES) {
            Kbuf[(size_t)nn * HD + i] = accK[j] + kb;
            Vbuf[(size_t)nn * HD + i] = accV[j] + vb;
            if (i < OD) Qs[(size_t)nn * OD + i] = accQ[j] + qb;
        }
    }
}

// ---------------- Kernel B: per-edge score + atomic scatter -------------------
// One wave (64 lanes) per edge. Lane l owns elements l and l+64 of the 128-dim
// (h0 = l>>4, h1 = h0+4); both share Qsum index l&15.
__global__ __launch_bounds__(256) void edge_kernel(
    const int* __restrict__ src, const int* __restrict__ dst,
    const float* __restrict__ Kbuf, const float* __restrict__ Vbuf,
    const float* __restrict__ Qs,
    float* __restrict__ wV, float* __restrict__ z)
{
    const int w = blockIdx.x * 4 + (threadIdx.x >> 6);
    const int l = threadIdx.x & 63;
    if (w >= ETOT) return;

    int s, d;
    if (w < NEDGE) { s = src[w]; d = dst[w]; }
    else           { s = w - NEDGE; d = s; }

    const float q = Qs[(size_t)d * OD + (l & 15)];
    const size_t kb = (size_t)s * HD;
    float p0 = Kbuf[kb + l]      * q;
    float p1 = Kbuf[kb + 64 + l] * q;

#pragma unroll
    for (int m = 1; m < 16; m <<= 1) {
        p0 += __shfl_xor(p0, m, 64);
        p1 += __shfl_xor(p1, m, 64);
    }
    // scores for heads g=l>>4 (p0) and g+4 (p1)
    const float s0 = __expf(fminf(5.f, fmaxf(-5.f, p0 * 0.25f)));
    const float s1 = __expf(fminf(5.f, fmaxf(-5.f, p1 * 0.25f)));

    const float v0 = Vbuf[kb + l]      * s0;
    const float v1 = Vbuf[kb + 64 + l] * s1;

    const size_t ob = (size_t)d * HD;
    unsafeAtomicAdd(&wV[ob + l],      v0);
    unsafeAtomicAdd(&wV[ob + 64 + l], v1);
    if ((l & 15) == 0) {
        unsafeAtomicAdd(&z[(size_t)d * NH + (l >> 4)],     s0);
        unsafeAtomicAdd(&z[(size_t)d * NH + 4 + (l >> 4)], s1);
    }
}

// ---------------- Kernel C: normalize + mean over heads -----------------------
__global__ __launch_bounds__(256) void final_kernel(
    const float* __restrict__ wV, const float* __restrict__ z,
    float* __restrict__ out)
{
    const int t = blockIdx.x * 256 + threadIdx.x;
    if (t >= NNODES * OD) return;
    const int n  = t >> 4;
    const int dd = t & 15;
    const float* wvp = wV + (size_t)n * HD + dd;
    const float* zp  = z  + (size_t)n * NH;
    float acc = 0.f;
#pragma unroll
    for (int hh = 0; hh < NH; hh++) acc += wvp[hh * OD] / zp[hh];
    out[t] = acc * 0.125f;
}

// ---------------- launch ------------------------------------------------------
extern "C" void kernel_launch(void* const* d_in, const int* in_sizes, int n_in,
                              void* d_out, int out_size, void* d_ws, size_t ws_size,
                              hipStream_t stream)
{
    const float* h  = (const float*)d_in[0];
    const float* Qw = (const float*)d_in[1];
    const float* Qb = (const float*)d_in[2];
    const float* Kw = (const float*)d_in[3];
    const float* Kb = (const float*)d_in[4];
    const float* Vw = (const float*)d_in[5];
    const float* Vb = (const float*)d_in[6];
    const int*   src = (const int*)d_in[7];
    const int*   dst = (const int*)d_in[8];

    float* ws   = (float*)d_ws;
    float* Kbuf = ws;                               // N*128
    float* Vbuf = Kbuf + (size_t)NNODES * HD;       // N*128
    float* Qs   = Vbuf + (size_t)NNODES * HD;       // N*16
    float* Wsum = Qs   + (size_t)NNODES * OD;       // 16*128
    float* Bsum = Wsum + OD * IND;                  // 16 (+pad)
    float* wV   = Bsum + 64;                        // N*128
    float* z    = wV   + (size_t)NNODES * HD;       // N*8

    // zero the accumulators (ws is poisoned 0xAA before every launch)
    hipMemsetAsync(wV, 0, ((size_t)NNODES * HD + (size_t)NNODES * NH) * sizeof(float), stream);

    prep_kernel<<<1, 256, 0, stream>>>(Qw, Qb, Wsum, Bsum);
    proj_kernel<<<(NNODES + 31) / 32, 256, 0, stream>>>(
        h, Kw, Kb, Vw, Vb, Wsum, Bsum, Kbuf, Vbuf, Qs);
    edge_kernel<<<ETOT / 4, 256, 0, stream>>>(src, dst, Kbuf, Vbuf, Qs, wV, z);
    final_kernel<<<(NNODES * OD + 255) / 256, 256, 0, stream>>>(wV, z, (float*)d_out);
}

// Round 2
// 596.342 us; speedup vs baseline: 1.7282x; 1.7282x over previous
//
#include <hip/hip_runtime.h>
#include <math.h>

#define NNODES 50000
#define IND    128
#define NH     8
#define OD     16
#define HD     128          // NH*OD
#define NEDGE  1600000
#define NB1    ((NNODES + 255) / 256)   // 196 scan blocks

// ---------------- Kernel 0: reduce Qw over heads -> Wsum[16][128], Bsum[16] ----
__global__ __launch_bounds__(256) void prep_kernel(
    const float* __restrict__ Qw, const float* __restrict__ Qb,
    float* __restrict__ Wsum, float* __restrict__ Bsum)
{
    for (int idx = threadIdx.x; idx < OD * IND; idx += 256) {
        int dd = idx >> 7;
        int k  = idx & 127;
        float s = 0.f;
#pragma unroll
        for (int hh = 0; hh < NH; hh++) s += Qw[(hh * OD + dd) * IND + k];
        Wsum[idx] = s;
    }
    if (threadIdx.x < OD) {
        float s = 0.f;
#pragma unroll
        for (int hh = 0; hh < NH; hh++) s += Qb[hh * OD + threadIdx.x];
        Bsum[threadIdx.x] = s;
    }
}

// ---------------- Kernel A: K/V/Qsum projections ------------------------------
__global__ __launch_bounds__(256) void proj_kernel(
    const float* __restrict__ hmat,
    const float* __restrict__ Kw, const float* __restrict__ Kb,
    const float* __restrict__ Vw, const float* __restrict__ Vb,
    const float* __restrict__ Wsum, const float* __restrict__ Bsum,
    float* __restrict__ Kbuf, float* __restrict__ Vbuf, float* __restrict__ Qs)
{
    __shared__ float hs[32 * IND];
    const int n0 = blockIdx.x * 32;

    for (int idx = threadIdx.x; idx < 32 * IND / 4; idx += 256) {
        int nn = n0 + (idx >> 5);
        float4 v = make_float4(0.f, 0.f, 0.f, 0.f);
        if (nn < NNODES) v = ((const float4*)hmat)[(size_t)n0 * 32 + idx];
        ((float4*)hs)[idx] = v;
    }
    __syncthreads();

    const int i  = threadIdx.x & 127;
    const int rg = threadIdx.x >> 7;

    float accK[16], accV[16], accQ[16];
#pragma unroll
    for (int j = 0; j < 16; j++) { accK[j] = 0.f; accV[j] = 0.f; accQ[j] = 0.f; }

    const float4* wkp = (const float4*)(Kw + (size_t)i * IND);
    const float4* wvp = (const float4*)(Vw + (size_t)i * IND);
    const float4* wqp = (const float4*)(Wsum + (size_t)(i & 15) * IND);

    for (int kq = 0; kq < IND / 4; kq++) {
        float4 wk = wkp[kq];
        float4 wv = wvp[kq];
        float4 wq = wqp[kq];
        const float* hb = hs + rg * 16 * IND + kq * 4;
#pragma unroll
        for (int j = 0; j < 16; j++) {
            float4 hh = *(const float4*)(hb + j * IND);
            accK[j] = fmaf(hh.w, wk.w, fmaf(hh.z, wk.z, fmaf(hh.y, wk.y, fmaf(hh.x, wk.x, accK[j]))));
            accV[j] = fmaf(hh.w, wv.w, fmaf(hh.z, wv.z, fmaf(hh.y, wv.y, fmaf(hh.x, wv.x, accV[j]))));
            accQ[j] = fmaf(hh.w, wq.w, fmaf(hh.z, wq.z, fmaf(hh.y, wq.y, fmaf(hh.x, wq.x, accQ[j]))));
        }
    }

    const float kb = Kb[i];
    const float vb = Vb[i];
    const float qb = Bsum[i & 15];
#pragma unroll
    for (int j = 0; j < 16; j++) {
        int nn = n0 + rg * 16 + j;
        if (nn < NNODES) {
            Kbuf[(size_t)nn * HD + i] = accK[j] + kb;
            Vbuf[(size_t)nn * HD + i] = accV[j] + vb;
            if (i < OD) Qs[(size_t)nn * OD + i] = accQ[j] + qb;
        }
    }
}

// ---------------- CSR build: histogram / scan / scatter -----------------------
__global__ __launch_bounds__(256) void hist_kernel(
    const int* __restrict__ dst, int* __restrict__ count)
{
    int e = blockIdx.x * 256 + threadIdx.x;
    if (e < NEDGE) atomicAdd(&count[dst[e]], 1);
}

__global__ __launch_bounds__(256) void scan1_kernel(
    const int* __restrict__ count, int* __restrict__ incl, int* __restrict__ bsum)
{
    __shared__ int sd[256];
    const int i = blockIdx.x * 256 + threadIdx.x;
    sd[threadIdx.x] = (i < NNODES) ? count[i] : 0;
    __syncthreads();
    for (int ofs = 1; ofs < 256; ofs <<= 1) {
        int x = (threadIdx.x >= ofs) ? sd[threadIdx.x - ofs] : 0;
        __syncthreads();
        sd[threadIdx.x] += x;
        __syncthreads();
    }
    if (i < NNODES) incl[i] = sd[threadIdx.x];
    if (threadIdx.x == 255) bsum[blockIdx.x] = sd[255];
}

__global__ __launch_bounds__(256) void scan2_kernel(int* __restrict__ bsum)
{
    __shared__ int sd[256];
    sd[threadIdx.x] = (threadIdx.x < NB1) ? bsum[threadIdx.x] : 0;
    __syncthreads();
    for (int ofs = 1; ofs < 256; ofs <<= 1) {
        int x = (threadIdx.x >= ofs) ? sd[threadIdx.x - ofs] : 0;
        __syncthreads();
        sd[threadIdx.x] += x;
        __syncthreads();
    }
    if (threadIdx.x < NB1) bsum[threadIdx.x] = sd[threadIdx.x];  // inclusive
}

__global__ __launch_bounds__(256) void scan3_kernel(
    const int* __restrict__ count, const int* __restrict__ incl,
    const int* __restrict__ bsum, int* __restrict__ offs, int* __restrict__ cursor)
{
    const int i = blockIdx.x * 256 + threadIdx.x;
    if (i >= NNODES) return;
    int prev = (blockIdx.x > 0) ? bsum[blockIdx.x - 1] : 0;
    int e = incl[i] - count[i] + prev;   // exclusive prefix
    offs[i]   = e;
    cursor[i] = e;
}

__global__ __launch_bounds__(256) void scatter_kernel(
    const int* __restrict__ src, const int* __restrict__ dst,
    int* __restrict__ cursor, int* __restrict__ eidx)
{
    int e = blockIdx.x * 256 + threadIdx.x;
    if (e < NEDGE) {
        int d = dst[e];
        int pos = atomicAdd(&cursor[d], 1);
        eidx[pos] = src[e];
    }
}

// ---------------- Gather-reduce: one wave per destination node ----------------
// Lane l owns feature elements (2l, 2l+1); head = l>>3, dim pair = l&7.
// Fuses the self-loop, softmax-weighted sum, normalization, and head-mean.
__global__ __launch_bounds__(256) void gather_kernel(
    const float* __restrict__ Kbuf, const float* __restrict__ Vbuf,
    const float* __restrict__ Qs,
    const int* __restrict__ offs, const int* __restrict__ count,
    const int* __restrict__ eidx,
    float* __restrict__ out)
{
    const int n = blockIdx.x * 4 + (threadIdx.x >> 6);
    const int l = threadIdx.x & 63;
    if (n >= NNODES) return;

    const float2* Kp = (const float2*)Kbuf;
    const float2* Vp = (const float2*)Vbuf;
    const float2  qv = ((const float2*)(Qs + (size_t)n * OD))[l & 7];

    const int off = offs[n];
    const int cnt = count[n];

    float a0 = 0.f, a1 = 0.f, zacc = 0.f;

    // self-loop (s = n)
    {
        float2 k = Kp[(size_t)n * 64 + l];
        float2 v = Vp[(size_t)n * 64 + l];
        float p = k.x * qv.x + k.y * qv.y;
        p += __shfl_xor(p, 1, 64);
        p += __shfl_xor(p, 2, 64);
        p += __shfl_xor(p, 4, 64);
        float sc = __expf(fminf(5.f, fmaxf(-5.f, p * 0.25f)));
        a0 = fmaf(v.x, sc, a0); a1 = fmaf(v.y, sc, a1); zacc += sc;
    }

    for (int base = 0; base < cnt; base += 64) {
        const int m = min(64, cnt - base);
        const int id = (base + l < cnt) ? eidx[off + base + l] : 0;

        int s0 = __shfl(id, 0, 64);
        float2 kc = Kp[(size_t)s0 * 64 + l];
        float2 vc = Vp[(size_t)s0 * 64 + l];

        for (int j = 0; j < m; j++) {
            float2 kn, vn;
            if (j + 1 < m) {
                int sn = __shfl(id, j + 1, 64);
                kn = Kp[(size_t)sn * 64 + l];
                vn = Vp[(size_t)sn * 64 + l];
            }
            float p = kc.x * qv.x + kc.y * qv.y;
            p += __shfl_xor(p, 1, 64);
            p += __shfl_xor(p, 2, 64);
            p += __shfl_xor(p, 4, 64);
            float sc = __expf(fminf(5.f, fmaxf(-5.f, p * 0.25f)));
            a0 = fmaf(vc.x, sc, a0); a1 = fmaf(vc.y, sc, a1); zacc += sc;
            kc = kn; vc = vn;
        }
    }

    // normalize per head, then mean over heads (reduce across lanes l^8,l^16,l^32)
    float r0 = a0 / zacc;
    float r1 = a1 / zacc;
    r0 += __shfl_xor(r0, 8, 64);  r0 += __shfl_xor(r0, 16, 64);  r0 += __shfl_xor(r0, 32, 64);
    r1 += __shfl_xor(r1, 8, 64);  r1 += __shfl_xor(r1, 16, 64);  r1 += __shfl_xor(r1, 32, 64);

    if (l < 8)
        ((float2*)(out + (size_t)n * OD))[l] = make_float2(r0 * 0.125f, r1 * 0.125f);
}

// ---------------- launch ------------------------------------------------------
extern "C" void kernel_launch(void* const* d_in, const int* in_sizes, int n_in,
                              void* d_out, int out_size, void* d_ws, size_t ws_size,
                              hipStream_t stream)
{
    const float* h  = (const float*)d_in[0];
    const float* Qw = (const float*)d_in[1];
    const float* Qb = (const float*)d_in[2];
    const float* Kw = (const float*)d_in[3];
    const float* Kb = (const float*)d_in[4];
    const float* Vw = (const float*)d_in[5];
    const float* Vb = (const float*)d_in[6];
    const int*   src = (const int*)d_in[7];
    const int*   dst = (const int*)d_in[8];

    char* ws = (char*)d_ws;
    float* Kbuf = (float*)ws;                          ws += (size_t)NNODES * HD * 4;
    float* Vbuf = (float*)ws;                          ws += (size_t)NNODES * HD * 4;
    float* Qs   = (float*)ws;                          ws += (size_t)NNODES * OD * 4;
    float* Wsum = (float*)ws;                          ws += OD * IND * 4;
    float* Bsum = (float*)ws;                          ws += 64 * 4;
    int*   count  = (int*)ws;                          ws += (size_t)NNODES * 4;
    int*   incl   = (int*)ws;                          ws += (size_t)NNODES * 4;
    int*   offs   = (int*)ws;                          ws += (size_t)NNODES * 4;
    int*   cursor = (int*)ws;                          ws += (size_t)NNODES * 4;
    int*   bsum   = (int*)ws;                          ws += 256 * 4;
    int*   eidx   = (int*)ws;                          ws += (size_t)NEDGE * 4;

    hipMemsetAsync(count, 0, (size_t)NNODES * 4, stream);

    prep_kernel<<<1, 256, 0, stream>>>(Qw, Qb, Wsum, Bsum);
    proj_kernel<<<(NNODES + 31) / 32, 256, 0, stream>>>(
        h, Kw, Kb, Vw, Vb, Wsum, Bsum, Kbuf, Vbuf, Qs);

    hist_kernel<<<(NEDGE + 255) / 256, 256, 0, stream>>>(dst, count);
    scan1_kernel<<<NB1, 256, 0, stream>>>(count, incl, bsum);
    scan2_kernel<<<1, 256, 0, stream>>>(bsum);
    scan3_kernel<<<NB1, 256, 0, stream>>>(count, incl, bsum, offs, cursor);
    scatter_kernel<<<(NEDGE + 255) / 256, 256, 0, stream>>>(src, dst, cursor, eidx);

    gather_kernel<<<(NNODES + 3) / 4, 256, 0, stream>>>(
        Kbuf, Vbuf, Qs, offs, count, eidx, (float*)d_out);
}

// Round 4
// 487.910 us; speedup vs baseline: 2.1123x; 1.2222x over previous
//
#include <hip/hip_runtime.h>
#include <hip/hip_fp16.h>
#include <math.h>

#define NNODES 50000
#define IND    128
#define NH     8
#define OD     16
#define HD     128          // NH*OD
#define NEDGE  1600000
#define PB     ((NNODES + 31) / 32)      // 1563 proj blocks
#define HB     ((NEDGE + 255) / 256)     // 6250 hist blocks
#define NB1    ((NNODES + 255) / 256)    // 196 scan blocks
#define WROW   132                        // padded Wsum row (2-way-free banks)

struct h2x2 { __half2 a, b; };           // one 8B packed load: 4 fp16

// ---------------- Fused kernel: proj (+Wsum build) and dst-histogram ----------
// Blocks [0, PB): K/V/Qsum projections, writing packed fp16 KV rows.
// Blocks [PB, PB+HB): histogram of dst (runs concurrently with proj).
__global__ __launch_bounds__(256) void proj_hist_kernel(
    const float* __restrict__ hmat,
    const float* __restrict__ Qw, const float* __restrict__ Qb,
    const float* __restrict__ Kw, const float* __restrict__ Kb,
    const float* __restrict__ Vw, const float* __restrict__ Vb,
    const int* __restrict__ dst,
    __half* __restrict__ KVbuf, float* __restrict__ Qs,
    int* __restrict__ count)
{
    if (blockIdx.x >= PB) {
        int e = (blockIdx.x - PB) * 256 + threadIdx.x;
        if (e < NEDGE) atomicAdd(&count[dst[e]], 1);
        return;
    }

    __shared__ float hs[32 * IND];
    __shared__ float wsum_s[OD * WROW];
    __shared__ float bsum_s[OD];

    const int n0 = blockIdx.x * 32;

    // stage h tile
    for (int idx = threadIdx.x; idx < 32 * IND / 4; idx += 256) {
        int nn = n0 + (idx >> 5);
        float4 v = make_float4(0.f, 0.f, 0.f, 0.f);
        if (nn < NNODES) v = ((const float4*)hmat)[(size_t)n0 * 32 + idx];
        ((float4*)hs)[idx] = v;
    }
    // build Wsum (sum of Qw over heads) in LDS, padded rows
    for (int t = threadIdx.x; t < OD * IND; t += 256) {
        int r = t >> 7, c = t & 127;
        float s = 0.f;
#pragma unroll
        for (int hh = 0; hh < NH; hh++) s += Qw[(hh * OD + r) * IND + c];
        wsum_s[r * WROW + c] = s;
    }
    if (threadIdx.x < OD) {
        float s = 0.f;
#pragma unroll
        for (int hh = 0; hh < NH; hh++) s += Qb[hh * OD + threadIdx.x];
        bsum_s[threadIdx.x] = s;
    }
    __syncthreads();

    const int i  = threadIdx.x & 127;
    const int rg = threadIdx.x >> 7;

    float accK[16], accV[16], accQ[16];
#pragma unroll
    for (int j = 0; j < 16; j++) { accK[j] = 0.f; accV[j] = 0.f; accQ[j] = 0.f; }

    const float4* wkp = (const float4*)(Kw + (size_t)i * IND);
    const float4* wvp = (const float4*)(Vw + (size_t)i * IND);
    const float*  wqb = wsum_s + (i & 15) * WROW;

    for (int kq = 0; kq < IND / 4; kq++) {
        float4 wk = wkp[kq];
        float4 wv = wvp[kq];
        float4 wq = *(const float4*)(wqb + kq * 4);
        const float* hb = hs + rg * 16 * IND + kq * 4;
#pragma unroll
        for (int j = 0; j < 16; j++) {
            float4 hh = *(const float4*)(hb + j * IND);
            accK[j] = fmaf(hh.w, wk.w, fmaf(hh.z, wk.z, fmaf(hh.y, wk.y, fmaf(hh.x, wk.x, accK[j]))));
            accV[j] = fmaf(hh.w, wv.w, fmaf(hh.z, wv.z, fmaf(hh.y, wv.y, fmaf(hh.x, wv.x, accV[j]))));
            accQ[j] = fmaf(hh.w, wq.w, fmaf(hh.z, wq.z, fmaf(hh.y, wq.y, fmaf(hh.x, wq.x, accQ[j]))));
        }
    }

    const float kb = Kb[i];
    const float vb = Vb[i];
    const float qb = bsum_s[i & 15];
#pragma unroll
    for (int j = 0; j < 16; j++) {
        int nn = n0 + rg * 16 + j;
        if (nn < NNODES) {
            __half* kv = KVbuf + (size_t)nn * 256;
            kv[i]       = __float2half_rn(accK[j] + kb);
            kv[128 + i] = __float2half_rn(accV[j] + vb);
            if (i < OD) Qs[(size_t)nn * OD + i] = accQ[j] + qb;
        }
    }
}

// ---------------- CSR build: scan / scatter -----------------------------------
__global__ __launch_bounds__(256) void scan1_kernel(
    const int* __restrict__ count, int* __restrict__ incl, int* __restrict__ bsum)
{
    __shared__ int sd[256];
    const int i = blockIdx.x * 256 + threadIdx.x;
    sd[threadIdx.x] = (i < NNODES) ? count[i] : 0;
    __syncthreads();
    for (int ofs = 1; ofs < 256; ofs <<= 1) {
        int x = (threadIdx.x >= ofs) ? sd[threadIdx.x - ofs] : 0;
        __syncthreads();
        sd[threadIdx.x] += x;
        __syncthreads();
    }
    if (i < NNODES) incl[i] = sd[threadIdx.x];
    if (threadIdx.x == 255) bsum[blockIdx.x] = sd[255];
}

__global__ __launch_bounds__(256) void scan2_kernel(int* __restrict__ bsum)
{
    __shared__ int sd[256];
    sd[threadIdx.x] = (threadIdx.x < NB1) ? bsum[threadIdx.x] : 0;
    __syncthreads();
    for (int ofs = 1; ofs < 256; ofs <<= 1) {
        int x = (threadIdx.x >= ofs) ? sd[threadIdx.x - ofs] : 0;
        __syncthreads();
        sd[threadIdx.x] += x;
        __syncthreads();
    }
    if (threadIdx.x < NB1) bsum[threadIdx.x] = sd[threadIdx.x];  // inclusive
}

__global__ __launch_bounds__(256) void scan3_kernel(
    const int* __restrict__ count, const int* __restrict__ incl,
    const int* __restrict__ bsum, int* __restrict__ offs, int* __restrict__ cursor)
{
    const int i = blockIdx.x * 256 + threadIdx.x;
    if (i >= NNODES) return;
    int prev = (blockIdx.x > 0) ? bsum[blockIdx.x - 1] : 0;
    int e = incl[i] - count[i] + prev;
    offs[i]   = e;
    cursor[i] = e;
}

__global__ __launch_bounds__(256) void scatter_kernel(
    const int* __restrict__ src, const int* __restrict__ dst,
    int* __restrict__ cursor, int* __restrict__ eidx)
{
    int e = blockIdx.x * 256 + threadIdx.x;
    if (e < NEDGE) {
        int d = dst[e];
        int pos = atomicAdd(&cursor[d], 1);
        eidx[pos] = src[e];
    }
}

// ---------------- Gather-reduce: one wave per destination node ----------------
// Packed fp16 KV row = 512B = 64 h2x2: lane l loads half-elems [4l,4l+3]
// (lanes 0-31 = K, lanes 32-63 = V). Score on K lanes (head l>>2, xor{1,2});
// V lanes grab the score via shfl from K lane (l&28) and keep 4 accumulators.
// Epilogue: per-head normalize, head mean via xor{4,8,16}, lanes 32-35 write
// one float4 each.
__global__ __launch_bounds__(256) void gather_kernel(
    const __half* __restrict__ KVbuf, const float* __restrict__ Qs,
    const int* __restrict__ offs, const int* __restrict__ count,
    const int* __restrict__ eidx,
    float* __restrict__ out)
{
    const int n = blockIdx.x * 4 + (threadIdx.x >> 6);
    const int l = threadIdx.x & 63;
    if (n >= NNODES) return;

    const h2x2* KVp = (const h2x2*)KVbuf;          // 64 h2x2 per node row
    const float4 qf = ((const float4*)(Qs + (size_t)n * OD))[l & 3];
    const int srcl = (l & 32) ? (l & 28) : l;       // V lane -> K lane 4*head

    const int off = offs[n];
    const int cnt = count[n];

    float a0 = 0.f, a1 = 0.f, a2 = 0.f, a3 = 0.f, zacc = 0.f;

    // self-loop (s = n)
    {
        h2x2 w = KVp[(size_t)n * 64 + l];
        float2 f0 = __half22float2(w.a);
        float2 f1 = __half22float2(w.b);
        float p = f0.x * qf.x + f0.y * qf.y + f1.x * qf.z + f1.y * qf.w;
        p += __shfl_xor(p, 1, 64);
        p += __shfl_xor(p, 2, 64);
        float sc = __expf(fminf(5.f, fmaxf(-5.f, p * 0.25f)));
        zacc += sc;
        float scv = __shfl(sc, srcl, 64);
        a0 = fmaf(f0.x, scv, a0); a1 = fmaf(f0.y, scv, a1);
        a2 = fmaf(f1.x, scv, a2); a3 = fmaf(f1.y, scv, a3);
    }

    for (int base = 0; base < cnt; base += 64) {
        const int m  = min(64, cnt - base);
        const int id = (base + l < cnt) ? eidx[off + base + l] : 0;

        int s0 = __shfl(id, 0, 64);
        h2x2 w = KVp[(size_t)s0 * 64 + l];

        for (int j = 0; j < m; j++) {
            h2x2 wn = w;
            if (j + 1 < m) {
                int sn = __shfl(id, j + 1, 64);
                wn = KVp[(size_t)sn * 64 + l];
            }
            float2 f0 = __half22float2(w.a);
            float2 f1 = __half22float2(w.b);
            float p = f0.x * qf.x + f0.y * qf.y + f1.x * qf.z + f1.y * qf.w;
            p += __shfl_xor(p, 1, 64);
            p += __shfl_xor(p, 2, 64);
            float sc = __expf(fminf(5.f, fmaxf(-5.f, p * 0.25f)));
            zacc += sc;
            float scv = __shfl(sc, srcl, 64);
            a0 = fmaf(f0.x, scv, a0); a1 = fmaf(f0.y, scv, a1);
            a2 = fmaf(f1.x, scv, a2); a3 = fmaf(f1.y, scv, a3);
            w = wn;
        }
    }

    // per-head normalize, then mean over heads
    const float zh = __shfl(zacc, srcl, 64);
    float r0 = a0 / zh, r1 = a1 / zh, r2 = a2 / zh, r3 = a3 / zh;
#pragma unroll
    for (int m = 4; m <= 16; m <<= 1) {
        r0 += __shfl_xor(r0, m, 64);
        r1 += __shfl_xor(r1, m, 64);
        r2 += __shfl_xor(r2, m, 64);
        r3 += __shfl_xor(r3, m, 64);
    }
    if (l >= 32 && l < 36)
        ((float4*)(out + (size_t)n * OD))[l - 32] =
            make_float4(r0 * 0.125f, r1 * 0.125f, r2 * 0.125f, r3 * 0.125f);
}

// ---------------- launch ------------------------------------------------------
extern "C" void kernel_launch(void* const* d_in, const int* in_sizes, int n_in,
                              void* d_out, int out_size, void* d_ws, size_t ws_size,
                              hipStream_t stream)
{
    const float* h  = (const float*)d_in[0];
    const float* Qw = (const float*)d_in[1];
    const float* Qb = (const float*)d_in[2];
    const float* Kw = (const float*)d_in[3];
    const float* Kb = (const float*)d_in[4];
    const float* Vw = (const float*)d_in[5];
    const float* Vb = (const float*)d_in[6];
    const int*   src = (const int*)d_in[7];
    const int*   dst = (const int*)d_in[8];

    char* ws = (char*)d_ws;
    __half* KVbuf = (__half*)ws;                       ws += (size_t)NNODES * 256 * 2;
    float*  Qs    = (float*)ws;                        ws += (size_t)NNODES * OD * 4;
    int*    count  = (int*)ws;                         ws += (size_t)NNODES * 4;
    int*    incl   = (int*)ws;                         ws += (size_t)NNODES * 4;
    int*    offs   = (int*)ws;                         ws += (size_t)NNODES * 4;
    int*    cursor = (int*)ws;                         ws += (size_t)NNODES * 4;
    int*    bsum   = (int*)ws;                         ws += 256 * 4;
    int*    eidx   = (int*)ws;                         ws += (size_t)NEDGE * 4;

    hipMemsetAsync(count, 0, (size_t)NNODES * 4, stream);

    proj_hist_kernel<<<PB + HB, 256, 0, stream>>>(
        h, Qw, Qb, Kw, Kb, Vw, Vb, dst, KVbuf, Qs, count);

    scan1_kernel<<<NB1, 256, 0, stream>>>(count, incl, bsum);
    scan2_kernel<<<1, 256, 0, stream>>>(bsum);
    scan3_kernel<<<NB1, 256, 0, stream>>>(count, incl, bsum, offs, cursor);
    scatter_kernel<<<HB, 256, 0, stream>>>(src, dst, cursor, eidx);

    gather_kernel<<<(NNODES + 3) / 4, 256, 0, stream>>>(
        KVbuf, Qs, offs, count, eidx, (float*)d_out);
}